// Round 7
// baseline (660.656 us; speedup 1.0000x reference)
//
#include <hip/hip_runtime.h>
#include <hip/hip_bf16.h>

typedef __bf16 bf16x8 __attribute__((ext_vector_type(8)));
typedef __bf16 bf16x4 __attribute__((ext_vector_type(4)));
typedef float floatx4 __attribute__((ext_vector_type(4)));

static constexpr int BB = 8;      // batch
static constexpr int NN = 1024;   // nodes
static constexpr int FF = 128;    // features
static constexpr int NT = 12;     // attention tasks: 0-5 rel, 6-8 fwd, 9-11 bwd

// workspace layout (bytes)
static constexpr size_t H_OFF  = 0;                                   // bf16 H^T [8][12][128][1024]
static constexpr size_t H_SZ   = (size_t)BB*NT*FF*NN*2;
static constexpr size_t EL_OFF = H_OFF + H_SZ;                        // f32 [96][1024]
static constexpr size_t EL_SZ  = (size_t)BB*NT*NN*4;
static constexpr size_t ER_OFF = EL_OFF + EL_SZ;                      // f32 [96][1024]
static constexpr size_t DV_OFF = ER_OFF + EL_SZ;                      // f32 [8][3][1024]
static constexpr size_t DV_SZ  = (size_t)BB*3*NN*4;
static constexpr size_t FV_OFF = DV_OFF + DV_SZ;                      // f32 folded [64][128]
static constexpr size_t FV_SZ  = (size_t)64*128*4;
static constexpr size_t FB_OFF = FV_OFF + FV_SZ;                      // f32 folded bias [64]
static constexpr size_t AB_OFF = FB_OFF + 256;                        // u32 bits [8][6][1024][32]

__device__ __forceinline__ unsigned short f2bf(float f) {
    union { float f; unsigned int i; } c; c.f = f;
    unsigned int r = (c.i + 0x7fffu + ((c.i >> 16) & 1u)) >> 16;   // RNE, finite inputs
    return (unsigned short)r;
}

// ---------------------------------------------------------------------------
// K0: setup. Blocks 0..63: folded attention vectors FV[v][k] (v=2t+side) =
// sum_f att_half[f] * fc_w[hch][f][k], and folded biases FB[v].
// Blocks 64..159: diagonal extract.
// ---------------------------------------------------------------------------
__global__ __launch_bounds__(256) void k0_setup(
    const float* __restrict__ adjs, const float* __restrict__ fc_w,
    const float* __restrict__ fc_b,
    const float* __restrict__ att_w, const float* __restrict__ att_b,
    const float* __restrict__ fwd_att_w, const float* __restrict__ fwd_att_b,
    const float* __restrict__ bwd_att_w, const float* __restrict__ bwd_att_b,
    float* __restrict__ FV, float* __restrict__ FB, float* __restrict__ DV)
{
    __shared__ float red[128];
    const int tid = threadIdx.x;
    const int bid = blockIdx.x;
    if (bid < 64) {
        const int v = bid;
        if (tid < 128) {
            float s = 0.f, bacc = 0.f;
            if (v < 24) {
                const int t = v >> 1, side = v & 1;
                const int hch = (t < 6) ? t : 5;
                const float* aw =
                    (t < 6) ? att_w + t * 256 :
                    (t < 9) ? fwd_att_w + (t - 6) * 256 : bwd_att_w + (t - 9) * 256;
                aw += side * 128;
                const float* W = fc_w + hch * 16384;
                for (int f = 0; f < 128; ++f) s += aw[f] * W[f * 128 + tid];
                bacc = fc_b[hch * 128 + tid] * aw[tid];
            }
            FV[v * 128 + tid] = s;
            red[tid] = bacc;
        }
        __syncthreads();
        if (tid == 0) {
            float s = 0.f;
            if (v < 24) {
                for (int i = 0; i < 128; ++i) s += red[i];
                if (v & 1) {
                    const int t = v >> 1;
                    s += (t < 6) ? att_b[t] : (t < 9) ? fwd_att_b[t - 6] : bwd_att_b[t - 9];
                }
            }
            FB[v] = s;
        }
    } else {
        const int gid = (bid - 64) * 256 + tid;   // (b*3+jj)*1024+n
        const int b   = gid / 3072;
        const int rem = gid % 3072;
        const int jj  = rem >> 10;
        const int n   = rem & 1023;
        DV[gid] = adjs[(((size_t)b * 9 + 3 + jj) * NN + n) * NN + n];
    }
}

// ---------------------------------------------------------------------------
// K_pack: adjacency -> row bitmasks. AB[b][s][row][w], s=0..2 -> t=0..2,
// s=3..5 -> slabs 6..8 (shared by fwd t=6-8 and bwd t=9-11).
// Wave ballots 64 binary floats into a uint64 -> 32x traffic cut for k5.
// ---------------------------------------------------------------------------
__global__ __launch_bounds__(256) void k_pack(const float* __restrict__ adjs,
                                              unsigned int* __restrict__ AB)
{
    const int wv   = threadIdx.x >> 6;
    const int lane = threadIdx.x & 63;
    const int bs   = blockIdx.x >> 4;          // 0..47 = b*6+s
    const int rg   = blockIdx.x & 15;          // rowgroup (64 rows)
    const int b    = bs / 6, s = bs % 6;
    const int ts   = (s < 3) ? s : s + 3;      // source slab index
    const float* slab = adjs + ((size_t)b * 9 + ts) * (size_t)NN * NN;
    unsigned int* dst = AB + (size_t)bs * NN * 32;

    for (int rr = 0; rr < 16; ++rr) {
        const int row = rg * 64 + wv * 16 + rr;
        const float* rp = slab + (size_t)row * NN;
        #pragma unroll 4
        for (int c = 0; c < 16; ++c) {
            float v = rp[c * 64 + lane];
            unsigned long long m = __ballot(v > 0.f);
            if (lane == 0)
                *reinterpret_cast<unsigned long long*>(&dst[(size_t)row * 32 + c * 2]) = m;
        }
    }
}

// ---------------------------------------------------------------------------
// K1: bf16 MFMA GEMM. C[8192 x 1792] = X[8192 x 128] @ Wcat^T + bias.
// ch 0 -> d_out (self term); ch 1..12 -> H^T bf16 [f][n]; ch 13 -> el/er.
// ---------------------------------------------------------------------------
__global__ __launch_bounds__(256) void k1_gemm(
    const float* __restrict__ x,
    const float* __restrict__ fc_w, const float* __restrict__ fc_b,
    const float* __restrict__ fwd_fc_w, const float* __restrict__ fwd_fc_b,
    const float* __restrict__ bwd_fc_w, const float* __restrict__ bwd_fc_b,
    const float* __restrict__ self_w, const float* __restrict__ self_b,
    const float* __restrict__ bias_in,
    const float* __restrict__ FV, const float* __restrict__ FB,
    float* __restrict__ out, unsigned short* __restrict__ H16T,
    float* __restrict__ el, float* __restrict__ er)
{
    __shared__ __align__(16) char smem[34816];
    __bf16* Als = (__bf16*)smem;                 // [64][136]
    __bf16* Bls = (__bf16*)(smem + 17408);       // [64][136]

    const int tid = threadIdx.x;
    const int m0 = blockIdx.y * 64;       // global row (b*1024+n)
    const int n0 = blockIdx.x * 64;       // global col (ch*128+f), ch13 has 1 tile
    const int ch = n0 >> 7;
    const int f0 = n0 & 127;

    const float* wsel; const float* bsel;
    if (ch == 0)       { wsel = self_w;                    bsel = self_b; }
    else if (ch <= 6)  { wsel = fc_w     + (ch-1)*16384;   bsel = fc_b     + (ch-1)*128; }
    else if (ch <= 9)  { wsel = fwd_fc_w + (ch-7)*16384;   bsel = fwd_fc_b + (ch-7)*128; }
    else if (ch <= 12) { wsel = bwd_fc_w + (ch-10)*16384;  bsel = bwd_fc_b + (ch-10)*128; }
    else               { wsel = FV;                        bsel = FB; }

    for (int it = 0; it < 8; ++it) {
        int idx = tid + it * 256;
        int r  = idx >> 5;
        int c4 = idx & 31;
        float4 va = *reinterpret_cast<const float4*>(x + (size_t)(m0 + r) * 128 + c4 * 4);
        *reinterpret_cast<bf16x4*>(&Als[r * 136 + c4 * 4]) =
            (bf16x4){(__bf16)va.x, (__bf16)va.y, (__bf16)va.z, (__bf16)va.w};
        float4 vb = *reinterpret_cast<const float4*>(wsel + (size_t)(f0 + r) * 128 + c4 * 4);
        *reinterpret_cast<bf16x4*>(&Bls[r * 136 + c4 * 4]) =
            (bf16x4){(__bf16)vb.x, (__bf16)vb.y, (__bf16)vb.z, (__bf16)vb.w};
    }
    __syncthreads();

    const int wid  = tid >> 6;
    const int lane = tid & 63;
    const int lrow = lane & 15;
    const int quad = lane >> 4;

    floatx4 acc[4];
    #pragma unroll
    for (int c = 0; c < 4; ++c) acc[c] = (floatx4){0.f, 0.f, 0.f, 0.f};

    #pragma unroll
    for (int kk = 0; kk < 4; ++kk) {
        const int k0 = kk * 32 + quad * 8;
        bf16x8 afr = *reinterpret_cast<const bf16x8*>(&Als[(wid * 16 + lrow) * 136 + k0]);
        #pragma unroll
        for (int c = 0; c < 4; ++c) {
            bf16x8 bfr = *reinterpret_cast<const bf16x8*>(&Bls[(c * 16 + lrow) * 136 + k0]);
            acc[c] = __builtin_amdgcn_mfma_f32_16x16x32_bf16(afr, bfr, acc[c], 0, 0, 0);
        }
    }

    // ---- epilogue via LDS transpose (reuses smem) ----
    __syncthreads();   // all MFMA LDS reads done

    const int b  = m0 >> 10;
    const int nb = m0 & 1023;

    if (ch >= 1 && ch <= 12) {
        // pack bf16 pairs (n-consecutive) into uint grid [fcol][n/2], stride 33
        unsigned int* SDH = (unsigned int*)smem;   // [64][33] = 8448 B
        #pragma unroll
        for (int c = 0; c < 4; ++c) {
            const int fl = c * 16 + lrow;
            const float bv = bsel[f0 + fl];
            #pragma unroll
            for (int p = 0; p < 2; ++p) {
                unsigned int pk = (unsigned int)f2bf(acc[c][2*p] + bv)
                                | ((unsigned int)f2bf(acc[c][2*p+1] + bv) << 16);
                SDH[fl * 33 + wid * 8 + quad * 2 + p] = pk;
            }
        }
        __syncthreads();
        const int f  = tid >> 2;
        const int ns = (tid & 3) * 16;
        unsigned int w[8];
        #pragma unroll
        for (int g = 0; g < 8; ++g) w[g] = SDH[f * 33 + ns / 2 + g];
        unsigned short* dst = H16T + (((size_t)b * NT + (ch - 1)) * FF + f0 + f) * NN + nb + ns;
        *reinterpret_cast<uint4*>(dst)     = (uint4){w[0], w[1], w[2], w[3]};
        *reinterpret_cast<uint4*>(dst + 8) = (uint4){w[4], w[5], w[6], w[7]};
    } else {
        // row-major f32 [n][fcol], stride 68 (2-way conflicts, free)
        float* SD = (float*)smem;                  // [64][68] = 17408 B
        #pragma unroll
        for (int c = 0; c < 4; ++c) {
            const int fl = c * 16 + lrow;
            float bv = bsel[f0 + fl];
            if (ch == 0) bv += bias_in[f0 + fl];
            #pragma unroll
            for (int r = 0; r < 4; ++r)
                SD[(wid * 16 + quad * 4 + r) * 68 + fl] = acc[c][r] + bv;
        }
        __syncthreads();
        if (ch == 0) {
            const int n  = tid >> 2;
            const int fs = (tid & 3) * 16;
            float* dst = out + (size_t)(m0 + n) * 128 + f0 + fs;
            #pragma unroll
            for (int g = 0; g < 4; ++g)
                reinterpret_cast<float4*>(dst)[g] =
                    *reinterpret_cast<const float4*>(&SD[n * 68 + fs + 4 * g]);
        } else {
            // ch 13: cols 2t -> el, 2t+1 -> er  (t = 0..11)
            const int n  = tid >> 2;
            const int c3 = tid & 3;
            #pragma unroll
            for (int tt = 0; tt < 3; ++tt) {
                const int t = c3 * 3 + tt;
                el[((size_t)b * NT + t) * NN + nb + n] = SD[n * 68 + 2 * t];
                er[((size_t)b * NT + t) * NN + nb + n] = SD[n * 68 + 2 * t + 1];
            }
        }
    }
}

// ---------------------------------------------------------------------------
// K5-dense v3: adjacency via bitmasks (AB). Register A-frags.
//  mode 0 (t<3, 6-8): row bits, 4 uint loads/lane/jt (was 32 float4-lanes)
//  mode 1 (t=3-5):    synthesized from dv
//  mode 2 (t=9-11):   fwd-slab row bits, quad-uniform word loads; bit lrow /
//                     16+lrow gives the transposed edge test. No transpose.
// ---------------------------------------------------------------------------
__global__ __launch_bounds__(256) void k5_dense(
    const unsigned int* __restrict__ AB, const unsigned short* __restrict__ H16T,
    const float* __restrict__ el, const float* __restrict__ er,
    const float* __restrict__ dv, float* __restrict__ out)
{
    __shared__ __align__(16) unsigned short Hls[144][72];  // [f][j], rows 128+ = ones
    __shared__ float lls[128];

    const int tid  = threadIdx.x;
    const int lane = tid & 63;
    const int wv   = tid >> 6;
    const int bi   = blockIdx.x;
    const int b    = bi & 7;               // batch -> XCD
    const int q    = bi >> 3;              // 0..95
    const int tq   = q >> 3;               // 0..11 schedule slot
    // schedule {0..5,6,9,7,10,8,11}: fwd/bwd of same slab adjacent for L2 reuse
    const int t    = (tq < 6) ? tq : (6 + (tq - 6) / 2 + ((tq - 6) & 1) * 3);
    const int i0   = (q & 7) * 128;
    const int bt   = b * NT + t;

    const unsigned short* hb = H16T + (size_t)bt * FF * NN;
    const float* elp = el + (size_t)bt * NN;
    const float* erp = er + (size_t)bt * NN;
    const float* dvp = dv + (size_t)(b * 3 + ((t - 3) % 3 + 3) % 3) * NN;

    int mode, smap = 0;
    if (t < 3)       { mode = 0; smap = t; }
    else if (t < 6)  { mode = 1; }
    else if (t < 9)  { mode = 0; smap = t - 3; }
    else             { mode = 2; smap = t - 6; }
    const unsigned int* ab = AB + (size_t)(b * 6 + smap) * NN * 32;

    const int lrow = lane & 15;
    const int quad = lane >> 4;
    const int kq   = quad * 8;
    const int r0   = i0 + wv * 32 + lrow;
    const int r1   = r0 + 16;
    const int wvw  = (i0 >> 5) + wv;       // mode-2 word index (quad-row word)

    const float el0 = elp[r0], el1 = elp[r1];
    bool g0 = true, g1 = true;
    if (mode == 1) { g0 = dvp[r0] > 0.f; g1 = dvp[r1] > 0.f; }

    // ones rows (128..143): row 128 = 1.0 for j<64, rest 0
    for (int idx = tid; idx < 16 * 72; idx += 256) {
        int r = idx / 72, k = idx % 72;
        Hls[128 + r][k] = (r == 0 && k < 64) ? (unsigned short)0x3F80u : (unsigned short)0u;
    }

    floatx4 acc[2][9];
    #pragma unroll
    for (int mt = 0; mt < 2; ++mt)
        #pragma unroll
        for (int nt = 0; nt < 9; ++nt) acc[mt][nt] = (floatx4){0.f, 0.f, 0.f, 0.f};

    union AFrag { unsigned short u[8]; bf16x8 v; };

    const int hf = tid >> 1;               // staging: thread -> H^T row
    const int jh = (tid & 1) * 32;

    for (int jt = 0; jt < 16; ++jt) {
        const int j0 = jt * 64;
        __syncthreads();                   // previous tile's Hls reads complete

        // issue H^T staging loads (land during frag build below)
        const unsigned short* hrow = hb + (size_t)hf * NN + j0 + jh;
        uint4 U0 = *reinterpret_cast<const uint4*>(hrow);
        uint4 U1 = *reinterpret_cast<const uint4*>(hrow + 8);
        uint4 U2 = *reinterpret_cast<const uint4*>(hrow + 16);
        uint4 U3 = *reinterpret_cast<const uint4*>(hrow + 24);

        // build A-fragments in registers (edge test from bitmasks)
        AFrag af[2][2];                    // [mt][kh]
        #pragma unroll
        for (int kh = 0; kh < 2; ++kh) {
            const int jb = j0 + kh * 32 + kq;
            float4 eA = *reinterpret_cast<const float4*>(erp + jb);
            float4 eB = *reinterpret_cast<const float4*>(erp + jb + 4);
            float ee[8] = {eA.x, eA.y, eA.z, eA.w, eB.x, eB.y, eB.z, eB.w};

            unsigned int w0 = 0, w1 = 0, wj[8];
            float d8[8];
            if (mode == 0) {
                w0 = ab[(size_t)r0 * 32 + jt * 2 + kh];
                w1 = ab[(size_t)r1 * 32 + jt * 2 + kh];
            } else if (mode == 1) {
                float4 D0 = *reinterpret_cast<const float4*>(dvp + jb);
                float4 D1 = *reinterpret_cast<const float4*>(dvp + jb + 4);
                d8[0]=D0.x;d8[1]=D0.y;d8[2]=D0.z;d8[3]=D0.w;
                d8[4]=D1.x;d8[5]=D1.y;d8[6]=D1.z;d8[7]=D1.w;
            } else {
                #pragma unroll
                for (int g = 0; g < 8; ++g)
                    wj[g] = ab[(size_t)(jb + g) * 32 + wvw];   // quad-uniform
            }

            #pragma unroll
            for (int g = 0; g < 8; ++g) {
                float e0 = el0 + ee[g];
                float e1 = el1 + ee[g];
                float v0 = (e0 >= 0.f) ? e0 : 0.01f * e0;
                float v1 = (e1 >= 0.f) ? e1 : 0.01f * e1;
                float p0 = __expf(v0);
                float p1 = __expf(v1);
                bool ed0, ed1;
                if (mode == 0) {
                    ed0 = (w0 >> (kq + g)) & 1;
                    ed1 = (w1 >> (kq + g)) & 1;
                } else if (mode == 1) {
                    bool dj = d8[g] > 0.f;
                    ed0 = g0 && dj;
                    ed1 = g1 && dj;
                } else {
                    ed0 = (wj[g] >> lrow) & 1;
                    ed1 = (wj[g] >> (16 + lrow)) & 1;
                }
                af[0][kh].u[g] = f2bf(ed0 ? p0 : 1.f);
                af[1][kh].u[g] = f2bf(ed1 ? p1 : 1.f);
            }
        }

        // commit H^T tile to LDS (loads have landed by now)
        *reinterpret_cast<uint4*>(&Hls[hf][jh])      = U0;
        *reinterpret_cast<uint4*>(&Hls[hf][jh + 8])  = U1;
        *reinterpret_cast<uint4*>(&Hls[hf][jh + 16]) = U2;
        *reinterpret_cast<uint4*>(&Hls[hf][jh + 24]) = U3;
        __syncthreads();

        // MFMA: 2 kh x 9 nt x 2 mt
        #pragma unroll
        for (int kh = 0; kh < 2; ++kh) {
            const int k0 = kh * 32 + kq;
            #pragma unroll
            for (int nt = 0; nt < 9; ++nt) {
                bf16x8 bfr = *reinterpret_cast<const bf16x8*>(&Hls[nt * 16 + lrow][k0]);
                acc[0][nt] = __builtin_amdgcn_mfma_f32_16x16x32_bf16(af[0][kh].v, bfr, acc[0][nt], 0, 0, 0);
                acc[1][nt] = __builtin_amdgcn_mfma_f32_16x16x32_bf16(af[1][kh].v, bfr, acc[1][nt], 0, 0, 0);
            }
        }
    }

    // ---- epilogue: l from n-tile 8 (col 0), scale, atomic add ----
    if (lrow == 0) {
        #pragma unroll
        for (int mt = 0; mt < 2; ++mt)
            #pragma unroll
            for (int r = 0; r < 4; ++r)
                lls[wv * 32 + mt * 16 + quad * 4 + r] = acc[mt][8][r];
    }
    __syncthreads();

    const float scale = (t >= 6) ? 0.5f : 1.0f;
    float* ob = out + ((size_t)b * NN + i0) * FF;
    #pragma unroll
    for (int mt = 0; mt < 2; ++mt) {
        #pragma unroll
        for (int r = 0; r < 4; ++r) {
            const int m = wv * 32 + mt * 16 + quad * 4 + r;
            const float inv = scale / lls[m];
            #pragma unroll
            for (int nt = 0; nt < 8; ++nt)
                atomicAdd(&ob[(size_t)m * FF + nt * 16 + lrow], acc[mt][nt][r] * inv);
        }
    }
}

// ---------------------------------------------------------------------------
// K6: relu in place
// ---------------------------------------------------------------------------
__global__ __launch_bounds__(256) void k6_relu(float* __restrict__ out)
{
    const int gid = blockIdx.x * 256 + threadIdx.x;
    out[gid] = fmaxf(out[gid], 0.f);
}

extern "C" void kernel_launch(void* const* d_in, const int* in_sizes, int n_in,
                              void* d_out, int out_size, void* d_ws, size_t ws_size,
                              hipStream_t stream)
{
    const float* x         = (const float*)d_in[0];
    const float* adjs      = (const float*)d_in[1];
    const float* fc_w      = (const float*)d_in[2];
    const float* fc_b      = (const float*)d_in[3];
    const float* att_w     = (const float*)d_in[4];
    const float* att_b     = (const float*)d_in[5];
    const float* fwd_fc_w  = (const float*)d_in[6];
    const float* fwd_fc_b  = (const float*)d_in[7];
    const float* fwd_att_w = (const float*)d_in[8];
    const float* fwd_att_b = (const float*)d_in[9];
    const float* bwd_fc_w  = (const float*)d_in[10];
    const float* bwd_fc_b  = (const float*)d_in[11];
    const float* bwd_att_w = (const float*)d_in[12];
    const float* bwd_att_b = (const float*)d_in[13];
    const float* self_w    = (const float*)d_in[14];
    const float* self_b    = (const float*)d_in[15];
    const float* bias_in   = (const float*)d_in[16];
    float* out = (float*)d_out;

    char* ws = (char*)d_ws;
    unsigned short* H16T = (unsigned short*)(ws + H_OFF);
    float* el = (float*)(ws + EL_OFF);
    float* er = (float*)(ws + ER_OFF);
    float* dv = (float*)(ws + DV_OFF);
    float* FV = (float*)(ws + FV_OFF);
    float* FB = (float*)(ws + FB_OFF);
    unsigned int* AB = (unsigned int*)(ws + AB_OFF);

    // K0: folded attention vectors + biases + diagonals
    k0_setup<<<160, 256, 0, stream>>>(adjs, fc_w, fc_b, att_w, att_b,
                                      fwd_att_w, fwd_att_b, bwd_att_w, bwd_att_b,
                                      FV, FB, dv);

    // K_pack: adjacency -> bitmasks (6 real slabs)
    k_pack<<<48 * 16, 256, 0, stream>>>(adjs, AB);

    // K1: 14-channel projection GEMM (ch0 -> out, 1..12 -> H^T, 13 -> el/er)
    k1_gemm<<<dim3(27, 128), 256, 0, stream>>>(
        x, fc_w, fc_b, fwd_fc_w, fwd_fc_b, bwd_fc_w, bwd_fc_b,
        self_w, self_b, bias_in, FV, FB, out, H16T, el, er);

    // K5: dense MFMA attention-apply, bitmask adjacency
    k5_dense<<<BB * NT * 8, 256, 0, stream>>>(AB, H16T, el, er, dv, out);

    // K6: relu
    k6_relu<<<out_size / 256, 256, 0, stream>>>(out);
}

// Round 8
// 485.932 us; speedup vs baseline: 1.3596x; 1.3596x over previous
//
#include <hip/hip_runtime.h>
#include <hip/hip_bf16.h>

typedef __bf16 bf16x8 __attribute__((ext_vector_type(8)));
typedef __bf16 bf16x4 __attribute__((ext_vector_type(4)));
typedef float floatx4 __attribute__((ext_vector_type(4)));

static constexpr int BB = 8;      // batch
static constexpr int NN = 1024;   // nodes
static constexpr int FF = 128;    // features
static constexpr int NT = 12;     // attention tasks: 0-5 rel, 6-8 fwd, 9-11 bwd

// workspace layout (bytes)
static constexpr size_t H_OFF  = 0;                                   // bf16 H^T [8][12][128][1024]
static constexpr size_t H_SZ   = (size_t)BB*NT*FF*NN*2;
static constexpr size_t EL_OFF = H_OFF + H_SZ;                        // f32 [96][1024]
static constexpr size_t EL_SZ  = (size_t)BB*NT*NN*4;
static constexpr size_t ER_OFF = EL_OFF + EL_SZ;                      // f32 [96][1024]
static constexpr size_t DV_OFF = ER_OFF + EL_SZ;                      // f32 [8][3][1024]
static constexpr size_t DV_SZ  = (size_t)BB*3*NN*4;
static constexpr size_t FV_OFF = DV_OFF + DV_SZ;                      // f32 folded [64][128]
static constexpr size_t FV_SZ  = (size_t)64*128*4;
static constexpr size_t FB_OFF = FV_OFF + FV_SZ;                      // f32 folded bias [64]
static constexpr size_t XL_OFF = FB_OFF + 256;                        // f32 exp(el) [96][1024]
static constexpr size_t XR_OFF = XL_OFF + EL_SZ;                      // f32 exp(er) [96][1024]

__device__ __forceinline__ unsigned short f2bf(float f) {
    union { float f; unsigned int i; } c; c.f = f;
    unsigned int r = (c.i + 0x7fffu + ((c.i >> 16) & 1u)) >> 16;   // RNE, finite inputs
    return (unsigned short)r;
}

// ---------------------------------------------------------------------------
// K0: setup. Blocks 0..63: folded attention vectors FV[v][k] (v=2t+side) =
// sum_f att_half[f] * fc_w[hch][f][k], and folded biases FB[v].
// Blocks 64..159: diagonal extract.
// ---------------------------------------------------------------------------
__global__ __launch_bounds__(256) void k0_setup(
    const float* __restrict__ adjs, const float* __restrict__ fc_w,
    const float* __restrict__ fc_b,
    const float* __restrict__ att_w, const float* __restrict__ att_b,
    const float* __restrict__ fwd_att_w, const float* __restrict__ fwd_att_b,
    const float* __restrict__ bwd_att_w, const float* __restrict__ bwd_att_b,
    float* __restrict__ FV, float* __restrict__ FB, float* __restrict__ DV)
{
    __shared__ float red[128];
    const int tid = threadIdx.x;
    const int bid = blockIdx.x;
    if (bid < 64) {
        const int v = bid;
        if (tid < 128) {
            float s = 0.f, bacc = 0.f;
            if (v < 24) {
                const int t = v >> 1, side = v & 1;
                const int hch = (t < 6) ? t : 5;
                const float* aw =
                    (t < 6) ? att_w + t * 256 :
                    (t < 9) ? fwd_att_w + (t - 6) * 256 : bwd_att_w + (t - 9) * 256;
                aw += side * 128;
                const float* W = fc_w + hch * 16384;
                for (int f = 0; f < 128; ++f) s += aw[f] * W[f * 128 + tid];
                bacc = fc_b[hch * 128 + tid] * aw[tid];
            }
            FV[v * 128 + tid] = s;
            red[tid] = bacc;
        }
        __syncthreads();
        if (tid == 0) {
            float s = 0.f;
            if (v < 24) {
                for (int i = 0; i < 128; ++i) s += red[i];
                if (v & 1) {
                    const int t = v >> 1;
                    s += (t < 6) ? att_b[t] : (t < 9) ? fwd_att_b[t - 6] : bwd_att_b[t - 9];
                }
            }
            FB[v] = s;
        }
    } else {
        const int gid = (bid - 64) * 256 + tid;   // (b*3+jj)*1024+n
        const int b   = gid / 3072;
        const int rem = gid % 3072;
        const int jj  = rem >> 10;
        const int n   = rem & 1023;
        DV[gid] = adjs[(((size_t)b * 9 + 3 + jj) * NN + n) * NN + n];
    }
}

// ---------------------------------------------------------------------------
// K1: bf16 MFMA GEMM. C[8192 x 1792] = X[8192 x 128] @ Wcat^T + bias.
// ch 0 -> d_out (self term); ch 1..12 -> H^T bf16 [f][n];
// ch 13 -> el/er + their exp tables (rank-1 exp factorization for k5).
// ---------------------------------------------------------------------------
__global__ __launch_bounds__(256) void k1_gemm(
    const float* __restrict__ x,
    const float* __restrict__ fc_w, const float* __restrict__ fc_b,
    const float* __restrict__ fwd_fc_w, const float* __restrict__ fwd_fc_b,
    const float* __restrict__ bwd_fc_w, const float* __restrict__ bwd_fc_b,
    const float* __restrict__ self_w, const float* __restrict__ self_b,
    const float* __restrict__ bias_in,
    const float* __restrict__ FV, const float* __restrict__ FB,
    float* __restrict__ out, unsigned short* __restrict__ H16T,
    float* __restrict__ el, float* __restrict__ er,
    float* __restrict__ xl, float* __restrict__ xr)
{
    __shared__ __align__(16) char smem[34816];
    __bf16* Als = (__bf16*)smem;                 // [64][136]
    __bf16* Bls = (__bf16*)(smem + 17408);       // [64][136]

    const int tid = threadIdx.x;
    const int m0 = blockIdx.y * 64;       // global row (b*1024+n)
    const int n0 = blockIdx.x * 64;       // global col (ch*128+f), ch13 has 1 tile
    const int ch = n0 >> 7;
    const int f0 = n0 & 127;

    const float* wsel; const float* bsel;
    if (ch == 0)       { wsel = self_w;                    bsel = self_b; }
    else if (ch <= 6)  { wsel = fc_w     + (ch-1)*16384;   bsel = fc_b     + (ch-1)*128; }
    else if (ch <= 9)  { wsel = fwd_fc_w + (ch-7)*16384;   bsel = fwd_fc_b + (ch-7)*128; }
    else if (ch <= 12) { wsel = bwd_fc_w + (ch-10)*16384;  bsel = bwd_fc_b + (ch-10)*128; }
    else               { wsel = FV;                        bsel = FB; }

    for (int it = 0; it < 8; ++it) {
        int idx = tid + it * 256;
        int r  = idx >> 5;
        int c4 = idx & 31;
        float4 va = *reinterpret_cast<const float4*>(x + (size_t)(m0 + r) * 128 + c4 * 4);
        *reinterpret_cast<bf16x4*>(&Als[r * 136 + c4 * 4]) =
            (bf16x4){(__bf16)va.x, (__bf16)va.y, (__bf16)va.z, (__bf16)va.w};
        float4 vb = *reinterpret_cast<const float4*>(wsel + (size_t)(f0 + r) * 128 + c4 * 4);
        *reinterpret_cast<bf16x4*>(&Bls[r * 136 + c4 * 4]) =
            (bf16x4){(__bf16)vb.x, (__bf16)vb.y, (__bf16)vb.z, (__bf16)vb.w};
    }
    __syncthreads();

    const int wid  = tid >> 6;
    const int lane = tid & 63;
    const int lrow = lane & 15;
    const int quad = lane >> 4;

    floatx4 acc[4];
    #pragma unroll
    for (int c = 0; c < 4; ++c) acc[c] = (floatx4){0.f, 0.f, 0.f, 0.f};

    #pragma unroll
    for (int kk = 0; kk < 4; ++kk) {
        const int k0 = kk * 32 + quad * 8;
        bf16x8 afr = *reinterpret_cast<const bf16x8*>(&Als[(wid * 16 + lrow) * 136 + k0]);
        #pragma unroll
        for (int c = 0; c < 4; ++c) {
            bf16x8 bfr = *reinterpret_cast<const bf16x8*>(&Bls[(c * 16 + lrow) * 136 + k0]);
            acc[c] = __builtin_amdgcn_mfma_f32_16x16x32_bf16(afr, bfr, acc[c], 0, 0, 0);
        }
    }

    // ---- epilogue via LDS transpose (reuses smem) ----
    __syncthreads();   // all MFMA LDS reads done

    const int b  = m0 >> 10;
    const int nb = m0 & 1023;

    if (ch >= 1 && ch <= 12) {
        // pack bf16 pairs (n-consecutive) into uint grid [fcol][n/2], stride 33
        unsigned int* SDH = (unsigned int*)smem;   // [64][33] = 8448 B
        #pragma unroll
        for (int c = 0; c < 4; ++c) {
            const int fl = c * 16 + lrow;
            const float bv = bsel[f0 + fl];
            #pragma unroll
            for (int p = 0; p < 2; ++p) {
                unsigned int pk = (unsigned int)f2bf(acc[c][2*p] + bv)
                                | ((unsigned int)f2bf(acc[c][2*p+1] + bv) << 16);
                SDH[fl * 33 + wid * 8 + quad * 2 + p] = pk;
            }
        }
        __syncthreads();
        const int f  = tid >> 2;
        const int ns = (tid & 3) * 16;
        unsigned int w[8];
        #pragma unroll
        for (int g = 0; g < 8; ++g) w[g] = SDH[f * 33 + ns / 2 + g];
        unsigned short* dst = H16T + (((size_t)b * NT + (ch - 1)) * FF + f0 + f) * NN + nb + ns;
        *reinterpret_cast<uint4*>(dst)     = (uint4){w[0], w[1], w[2], w[3]};
        *reinterpret_cast<uint4*>(dst + 8) = (uint4){w[4], w[5], w[6], w[7]};
    } else {
        // row-major f32 [n][fcol], stride 68 (2-way conflicts, free)
        float* SD = (float*)smem;                  // [64][68] = 17408 B
        #pragma unroll
        for (int c = 0; c < 4; ++c) {
            const int fl = c * 16 + lrow;
            float bv = bsel[f0 + fl];
            if (ch == 0) bv += bias_in[f0 + fl];
            #pragma unroll
            for (int r = 0; r < 4; ++r)
                SD[(wid * 16 + quad * 4 + r) * 68 + fl] = acc[c][r] + bv;
        }
        __syncthreads();
        if (ch == 0) {
            const int n  = tid >> 2;
            const int fs = (tid & 3) * 16;
            float* dst = out + (size_t)(m0 + n) * 128 + f0 + fs;
            #pragma unroll
            for (int g = 0; g < 4; ++g)
                reinterpret_cast<float4*>(dst)[g] =
                    *reinterpret_cast<const float4*>(&SD[n * 68 + fs + 4 * g]);
        } else {
            // ch 13: cols 2t -> el, 2t+1 -> er  (t = 0..11) + exp tables
            const int n  = tid >> 2;
            const int c3 = tid & 3;
            #pragma unroll
            for (int tt = 0; tt < 3; ++tt) {
                const int t = c3 * 3 + tt;
                const float ev = SD[n * 68 + 2 * t];
                const float rv = SD[n * 68 + 2 * t + 1];
                const size_t o = ((size_t)b * NT + t) * NN + nb + n;
                el[o] = ev;  xl[o] = __expf(ev);
                er[o] = rv;  xr[o] = __expf(rv);
            }
        }
    }
}

// ---------------------------------------------------------------------------
// K5-dense v4: R6 structure (float adjacency, register A-frags) with the
// exp factorized out: e = el_i + er_j; e>=0 -> q = exp(el_i)*exp(er_j)
// (tables xl/xr); e<0 -> q = 1 + 0.01e + 5e-5 e^2 (2 FMA, rel err < 2e-5).
// No transcendentals in the j-loop.
// ---------------------------------------------------------------------------
__global__ __launch_bounds__(256) void k5_dense(
    const float* __restrict__ adjs, const unsigned short* __restrict__ H16T,
    const float* __restrict__ el, const float* __restrict__ er,
    const float* __restrict__ xl, const float* __restrict__ xr,
    const float* __restrict__ dv, float* __restrict__ out)
{
    __shared__ __align__(16) unsigned short Hls[144][72];  // [f][j], rows 128+ = ones
    __shared__ float lls[128];

    const int tid  = threadIdx.x;
    const int lane = tid & 63;
    const int wv   = tid >> 6;
    const int bi   = blockIdx.x;
    const int b    = bi & 7;               // batch -> XCD
    const int q    = bi >> 3;              // 0..95
    const int tq   = q >> 3;               // 0..11 schedule slot
    // schedule {0..5,6,9,7,10,8,11}: fwd/bwd of same slab adjacent for L2 reuse
    const int t    = (tq < 6) ? tq : (6 + (tq - 6) / 2 + ((tq - 6) & 1) * 3);
    const int i0   = (q & 7) * 128;
    const int bt   = b * NT + t;

    const unsigned short* hb = H16T + (size_t)bt * FF * NN;
    const float* elp = el + (size_t)bt * NN;
    const float* erp = er + (size_t)bt * NN;
    const float* xrp = xr + (size_t)bt * NN;
    const float* dvp = dv + (size_t)(b * 3 + ((t - 3) % 3 + 3) % 3) * NN;

    int mode; const float* slab = nullptr;
    if (t < 3)       { mode = 0; slab = adjs + ((size_t)b * 9 + t) * (size_t)NN * NN; }
    else if (t < 6)  { mode = 1; }
    else if (t < 9)  { mode = 0; slab = adjs + ((size_t)b * 9 + t) * (size_t)NN * NN; }
    else             { mode = 2; slab = adjs + ((size_t)b * 9 + (t - 3)) * (size_t)NN * NN; }

    const int lrow = lane & 15;
    const int quad = lane >> 4;
    const int kq   = quad * 8;
    const int r0   = i0 + wv * 32 + lrow;
    const int r1   = r0 + 16;

    const float el0 = elp[r0], el1 = elp[r1];
    const float Ei0 = xl[(size_t)bt * NN + r0];
    const float Ei1 = xl[(size_t)bt * NN + r1];
    bool g0 = true, g1 = true;
    if (mode == 1) { g0 = dvp[r0] > 0.f; g1 = dvp[r1] > 0.f; }

    // ones rows (128..143): row 128 = 1.0 for j<64, rest 0
    for (int idx = tid; idx < 16 * 72; idx += 256) {
        int r = idx / 72, k = idx % 72;
        Hls[128 + r][k] = (r == 0 && k < 64) ? (unsigned short)0x3F80u : (unsigned short)0u;
    }

    floatx4 acc[2][9];
    #pragma unroll
    for (int mt = 0; mt < 2; ++mt)
        #pragma unroll
        for (int nt = 0; nt < 9; ++nt) acc[mt][nt] = (floatx4){0.f, 0.f, 0.f, 0.f};

    union AFrag { unsigned short u[8]; bf16x8 v; };

    const int hf = tid >> 1;               // staging: thread -> H^T row
    const int jh = (tid & 1) * 32;

    for (int jt = 0; jt < 16; ++jt) {
        const int j0 = jt * 64;
        __syncthreads();                   // previous tile's Hls reads complete

        // issue H^T staging loads (land during frag build below)
        const unsigned short* hrow = hb + (size_t)hf * NN + j0 + jh;
        uint4 U0 = *reinterpret_cast<const uint4*>(hrow);
        uint4 U1 = *reinterpret_cast<const uint4*>(hrow + 8);
        uint4 U2 = *reinterpret_cast<const uint4*>(hrow + 16);
        uint4 U3 = *reinterpret_cast<const uint4*>(hrow + 24);

        // build A-fragments in registers
        AFrag af[2][2];                    // [mt][kh]
        #pragma unroll
        for (int kh = 0; kh < 2; ++kh) {
            const int jb = j0 + kh * 32 + kq;
            float4 eA = *reinterpret_cast<const float4*>(erp + jb);
            float4 eB = *reinterpret_cast<const float4*>(erp + jb + 4);
            float ee[8] = {eA.x, eA.y, eA.z, eA.w, eB.x, eB.y, eB.z, eB.w};
            float4 xA = *reinterpret_cast<const float4*>(xrp + jb);
            float4 xB = *reinterpret_cast<const float4*>(xrp + jb + 4);
            float xx[8] = {xA.x, xA.y, xA.z, xA.w, xB.x, xB.y, xB.z, xB.w};
            float a0[8], a1[8];
            if (mode == 0) {
                float4 A0 = *reinterpret_cast<const float4*>(slab + (size_t)r0 * NN + jb);
                float4 A1 = *reinterpret_cast<const float4*>(slab + (size_t)r0 * NN + jb + 4);
                float4 B0 = *reinterpret_cast<const float4*>(slab + (size_t)r1 * NN + jb);
                float4 B1 = *reinterpret_cast<const float4*>(slab + (size_t)r1 * NN + jb + 4);
                a0[0]=A0.x;a0[1]=A0.y;a0[2]=A0.z;a0[3]=A0.w;a0[4]=A1.x;a0[5]=A1.y;a0[6]=A1.z;a0[7]=A1.w;
                a1[0]=B0.x;a1[1]=B0.y;a1[2]=B0.z;a1[3]=B0.w;a1[4]=B1.x;a1[5]=B1.y;a1[6]=B1.z;a1[7]=B1.w;
            } else if (mode == 1) {
                float4 D0 = *reinterpret_cast<const float4*>(dvp + jb);
                float4 D1 = *reinterpret_cast<const float4*>(dvp + jb + 4);
                a0[0]=D0.x;a0[1]=D0.y;a0[2]=D0.z;a0[3]=D0.w;a0[4]=D1.x;a0[5]=D1.y;a0[6]=D1.z;a0[7]=D1.w;
                #pragma unroll
                for (int g = 0; g < 8; ++g) a1[g] = a0[g];
            } else {
                #pragma unroll
                for (int g = 0; g < 8; ++g) {
                    const float* col = slab + (size_t)(jb + g) * NN;
                    a0[g] = col[r0];       // lanes of a quad read 16 consecutive i
                    a1[g] = col[r1];
                }
            }
            #pragma unroll
            for (int g = 0; g < 8; ++g) {
                float e0 = el0 + ee[g];
                float e1 = el1 + ee[g];
                // exp(leaky(e)): e>=0 -> Ei*Ej; e<0 -> 1+0.01e+5e-5e^2
                float p0 = (e0 >= 0.f) ? Ei0 * xx[g]
                                       : fmaf(e0, fmaf(e0, 5.0e-5f, 0.01f), 1.0f);
                float p1 = (e1 >= 0.f) ? Ei1 * xx[g]
                                       : fmaf(e1, fmaf(e1, 5.0e-5f, 0.01f), 1.0f);
                bool ed0 = g0 && (a0[g] > 0.f);
                bool ed1 = g1 && (a1[g] > 0.f);
                af[0][kh].u[g] = f2bf(ed0 ? p0 : 1.f);
                af[1][kh].u[g] = f2bf(ed1 ? p1 : 1.f);
            }
        }

        // commit H^T tile to LDS (loads have landed by now)
        *reinterpret_cast<uint4*>(&Hls[hf][jh])      = U0;
        *reinterpret_cast<uint4*>(&Hls[hf][jh + 8])  = U1;
        *reinterpret_cast<uint4*>(&Hls[hf][jh + 16]) = U2;
        *reinterpret_cast<uint4*>(&Hls[hf][jh + 24]) = U3;
        __syncthreads();

        // MFMA: 2 kh x 9 nt x 2 mt
        #pragma unroll
        for (int kh = 0; kh < 2; ++kh) {
            const int k0 = kh * 32 + kq;
            #pragma unroll
            for (int nt = 0; nt < 9; ++nt) {
                bf16x8 bfr = *reinterpret_cast<const bf16x8*>(&Hls[nt * 16 + lrow][k0]);
                acc[0][nt] = __builtin_amdgcn_mfma_f32_16x16x32_bf16(af[0][kh].v, bfr, acc[0][nt], 0, 0, 0);
                acc[1][nt] = __builtin_amdgcn_mfma_f32_16x16x32_bf16(af[1][kh].v, bfr, acc[1][nt], 0, 0, 0);
            }
        }
    }

    // ---- epilogue: l from n-tile 8 (col 0), scale, atomic add ----
    if (lrow == 0) {
        #pragma unroll
        for (int mt = 0; mt < 2; ++mt)
            #pragma unroll
            for (int r = 0; r < 4; ++r)
                lls[wv * 32 + mt * 16 + quad * 4 + r] = acc[mt][8][r];
    }
    __syncthreads();

    const float scale = (t >= 6) ? 0.5f : 1.0f;
    float* ob = out + ((size_t)b * NN + i0) * FF;
    #pragma unroll
    for (int mt = 0; mt < 2; ++mt) {
        #pragma unroll
        for (int r = 0; r < 4; ++r) {
            const int m = wv * 32 + mt * 16 + quad * 4 + r;
            const float inv = scale / lls[m];
            #pragma unroll
            for (int nt = 0; nt < 8; ++nt)
                atomicAdd(&ob[(size_t)m * FF + nt * 16 + lrow], acc[mt][nt][r] * inv);
        }
    }
}

// ---------------------------------------------------------------------------
// K6: relu in place
// ---------------------------------------------------------------------------
__global__ __launch_bounds__(256) void k6_relu(float* __restrict__ out)
{
    const int gid = blockIdx.x * 256 + threadIdx.x;
    out[gid] = fmaxf(out[gid], 0.f);
}

extern "C" void kernel_launch(void* const* d_in, const int* in_sizes, int n_in,
                              void* d_out, int out_size, void* d_ws, size_t ws_size,
                              hipStream_t stream)
{
    const float* x         = (const float*)d_in[0];
    const float* adjs      = (const float*)d_in[1];
    const float* fc_w      = (const float*)d_in[2];
    const float* fc_b      = (const float*)d_in[3];
    const float* att_w     = (const float*)d_in[4];
    const float* att_b     = (const float*)d_in[5];
    const float* fwd_fc_w  = (const float*)d_in[6];
    const float* fwd_fc_b  = (const float*)d_in[7];
    const float* fwd_att_w = (const float*)d_in[8];
    const float* fwd_att_b = (const float*)d_in[9];
    const float* bwd_fc_w  = (const float*)d_in[10];
    const float* bwd_fc_b  = (const float*)d_in[11];
    const float* bwd_att_w = (const float*)d_in[12];
    const float* bwd_att_b = (const float*)d_in[13];
    const float* self_w    = (const float*)d_in[14];
    const float* self_b    = (const float*)d_in[15];
    const float* bias_in   = (const float*)d_in[16];
    float* out = (float*)d_out;

    char* ws = (char*)d_ws;
    unsigned short* H16T = (unsigned short*)(ws + H_OFF);
    float* el = (float*)(ws + EL_OFF);
    float* er = (float*)(ws + ER_OFF);
    float* dv = (float*)(ws + DV_OFF);
    float* FV = (float*)(ws + FV_OFF);
    float* FB = (float*)(ws + FB_OFF);
    float* xl = (float*)(ws + XL_OFF);
    float* xr = (float*)(ws + XR_OFF);

    // K0: folded attention vectors + biases + diagonals
    k0_setup<<<160, 256, 0, stream>>>(adjs, fc_w, fc_b, att_w, att_b,
                                      fwd_att_w, fwd_att_b, bwd_att_w, bwd_att_b,
                                      FV, FB, dv);

    // K1: 14-channel projection GEMM (ch0 -> out, 1..12 -> H^T, 13 -> el/er/exp)
    k1_gemm<<<dim3(27, 128), 256, 0, stream>>>(
        x, fc_w, fc_b, fwd_fc_w, fwd_fc_b, bwd_fc_w, bwd_fc_b,
        self_w, self_b, bias_in, FV, FB, out, H16T, el, er, xl, xr);

    // K5: dense MFMA attention-apply, factorized exp
    k5_dense<<<BB * NT * 8, 256, 0, stream>>>(adjs, H16T, el, er, xl, xr, dv, out);

    // K6: relu
    k6_relu<<<out_size / 256, 256, 0, stream>>>(out);
}

// Round 9
// 479.435 us; speedup vs baseline: 1.3780x; 1.0136x over previous
//
#include <hip/hip_runtime.h>
#include <hip/hip_bf16.h>

typedef __bf16 bf16x8 __attribute__((ext_vector_type(8)));
typedef __bf16 bf16x4 __attribute__((ext_vector_type(4)));
typedef float floatx4 __attribute__((ext_vector_type(4)));

static constexpr int BB = 8;      // batch
static constexpr int NN = 1024;   // nodes
static constexpr int FF = 128;    // features
static constexpr int NT = 12;     // attention tasks: 0-5 rel, 6-8 fwd, 9-11 bwd

// workspace layout (bytes)
static constexpr size_t H_OFF  = 0;                                   // bf16 H^T [8][12][128][1024]
static constexpr size_t H_SZ   = (size_t)BB*NT*FF*NN*2;
static constexpr size_t EL_OFF = H_OFF + H_SZ;                        // f32 [96][1024]
static constexpr size_t EL_SZ  = (size_t)BB*NT*NN*4;
static constexpr size_t ER_OFF = EL_OFF + EL_SZ;                      // f32 [96][1024]
static constexpr size_t DV_OFF = ER_OFF + EL_SZ;                      // f32 [8][3][1024]
static constexpr size_t DV_SZ  = (size_t)BB*3*NN*4;
static constexpr size_t FV_OFF = DV_OFF + DV_SZ;                      // f32 folded [64][128]
static constexpr size_t FV_SZ  = (size_t)64*128*4;
static constexpr size_t FB_OFF = FV_OFF + FV_SZ;                      // f32 folded bias [64]
static constexpr size_t XL_OFF = FB_OFF + 256;                        // f32 exp(el) [96][1024]
static constexpr size_t XR_OFF = XL_OFF + EL_SZ;                      // f32 exp(er) [96][1024]

__device__ __forceinline__ unsigned short f2bf(float f) {
    union { float f; unsigned int i; } c; c.f = f;
    unsigned int r = (c.i + 0x7fffu + ((c.i >> 16) & 1u)) >> 16;   // RNE, finite inputs
    return (unsigned short)r;
}
// pack two positive floats to bf16x2 (round-half-up, 4 ops) — k5 hot path
__device__ __forceinline__ unsigned int pk2bf(float lo, float hi) {
    unsigned int il = __float_as_uint(lo) + 0x8000u;
    unsigned int ih = __float_as_uint(hi) + 0x8000u;
    return (il >> 16) | (ih & 0xffff0000u);
}

// ---------------------------------------------------------------------------
// K0: setup. Blocks 0..63: folded attention vectors FV[v][k] (v=2t+side) =
// sum_f att_half[f] * fc_w[hch][f][k], and folded biases FB[v].
// Blocks 64..159: diagonal extract.
// ---------------------------------------------------------------------------
__global__ __launch_bounds__(256) void k0_setup(
    const float* __restrict__ adjs, const float* __restrict__ fc_w,
    const float* __restrict__ fc_b,
    const float* __restrict__ att_w, const float* __restrict__ att_b,
    const float* __restrict__ fwd_att_w, const float* __restrict__ fwd_att_b,
    const float* __restrict__ bwd_att_w, const float* __restrict__ bwd_att_b,
    float* __restrict__ FV, float* __restrict__ FB, float* __restrict__ DV)
{
    __shared__ float red[128];
    const int tid = threadIdx.x;
    const int bid = blockIdx.x;
    if (bid < 64) {
        const int v = bid;
        if (tid < 128) {
            float s = 0.f, bacc = 0.f;
            if (v < 24) {
                const int t = v >> 1, side = v & 1;
                const int hch = (t < 6) ? t : 5;
                const float* aw =
                    (t < 6) ? att_w + t * 256 :
                    (t < 9) ? fwd_att_w + (t - 6) * 256 : bwd_att_w + (t - 9) * 256;
                aw += side * 128;
                const float* W = fc_w + hch * 16384;
                for (int f = 0; f < 128; ++f) s += aw[f] * W[f * 128 + tid];
                bacc = fc_b[hch * 128 + tid] * aw[tid];
            }
            FV[v * 128 + tid] = s;
            red[tid] = bacc;
        }
        __syncthreads();
        if (tid == 0) {
            float s = 0.f;
            if (v < 24) {
                for (int i = 0; i < 128; ++i) s += red[i];
                if (v & 1) {
                    const int t = v >> 1;
                    s += (t < 6) ? att_b[t] : (t < 9) ? fwd_att_b[t - 6] : bwd_att_b[t - 9];
                }
            }
            FB[v] = s;
        }
    } else {
        const int gid = (bid - 64) * 256 + tid;   // (b*3+jj)*1024+n
        const int b   = gid / 3072;
        const int rem = gid % 3072;
        const int jj  = rem >> 10;
        const int n   = rem & 1023;
        DV[gid] = adjs[(((size_t)b * 9 + 3 + jj) * NN + n) * NN + n];
    }
}

// ---------------------------------------------------------------------------
// K1: bf16 MFMA GEMM. C[8192 x 1792] = X[8192 x 128] @ Wcat^T + bias.
// ch 0 -> d_out (self term); ch 1..12 -> H^T bf16 [f][n];
// ch 13 -> el/er + their exp tables (rank-1 exp factorization for k5).
// ---------------------------------------------------------------------------
__global__ __launch_bounds__(256) void k1_gemm(
    const float* __restrict__ x,
    const float* __restrict__ fc_w, const float* __restrict__ fc_b,
    const float* __restrict__ fwd_fc_w, const float* __restrict__ fwd_fc_b,
    const float* __restrict__ bwd_fc_w, const float* __restrict__ bwd_fc_b,
    const float* __restrict__ self_w, const float* __restrict__ self_b,
    const float* __restrict__ bias_in,
    const float* __restrict__ FV, const float* __restrict__ FB,
    float* __restrict__ out, unsigned short* __restrict__ H16T,
    float* __restrict__ el, float* __restrict__ er,
    float* __restrict__ xl, float* __restrict__ xr)
{
    __shared__ __align__(16) char smem[34816];
    __bf16* Als = (__bf16*)smem;                 // [64][136]
    __bf16* Bls = (__bf16*)(smem + 17408);       // [64][136]

    const int tid = threadIdx.x;
    const int m0 = blockIdx.y * 64;       // global row (b*1024+n)
    const int n0 = blockIdx.x * 64;       // global col (ch*128+f), ch13 has 1 tile
    const int ch = n0 >> 7;
    const int f0 = n0 & 127;

    const float* wsel; const float* bsel;
    if (ch == 0)       { wsel = self_w;                    bsel = self_b; }
    else if (ch <= 6)  { wsel = fc_w     + (ch-1)*16384;   bsel = fc_b     + (ch-1)*128; }
    else if (ch <= 9)  { wsel = fwd_fc_w + (ch-7)*16384;   bsel = fwd_fc_b + (ch-7)*128; }
    else if (ch <= 12) { wsel = bwd_fc_w + (ch-10)*16384;  bsel = bwd_fc_b + (ch-10)*128; }
    else               { wsel = FV;                        bsel = FB; }

    for (int it = 0; it < 8; ++it) {
        int idx = tid + it * 256;
        int r  = idx >> 5;
        int c4 = idx & 31;
        float4 va = *reinterpret_cast<const float4*>(x + (size_t)(m0 + r) * 128 + c4 * 4);
        *reinterpret_cast<bf16x4*>(&Als[r * 136 + c4 * 4]) =
            (bf16x4){(__bf16)va.x, (__bf16)va.y, (__bf16)va.z, (__bf16)va.w};
        float4 vb = *reinterpret_cast<const float4*>(wsel + (size_t)(f0 + r) * 128 + c4 * 4);
        *reinterpret_cast<bf16x4*>(&Bls[r * 136 + c4 * 4]) =
            (bf16x4){(__bf16)vb.x, (__bf16)vb.y, (__bf16)vb.z, (__bf16)vb.w};
    }
    __syncthreads();

    const int wid  = tid >> 6;
    const int lane = tid & 63;
    const int lrow = lane & 15;
    const int quad = lane >> 4;

    floatx4 acc[4];
    #pragma unroll
    for (int c = 0; c < 4; ++c) acc[c] = (floatx4){0.f, 0.f, 0.f, 0.f};

    #pragma unroll
    for (int kk = 0; kk < 4; ++kk) {
        const int k0 = kk * 32 + quad * 8;
        bf16x8 afr = *reinterpret_cast<const bf16x8*>(&Als[(wid * 16 + lrow) * 136 + k0]);
        #pragma unroll
        for (int c = 0; c < 4; ++c) {
            bf16x8 bfr = *reinterpret_cast<const bf16x8*>(&Bls[(c * 16 + lrow) * 136 + k0]);
            acc[c] = __builtin_amdgcn_mfma_f32_16x16x32_bf16(afr, bfr, acc[c], 0, 0, 0);
        }
    }

    // ---- epilogue via LDS transpose (reuses smem) ----
    __syncthreads();   // all MFMA LDS reads done

    const int b  = m0 >> 10;
    const int nb = m0 & 1023;

    if (ch >= 1 && ch <= 12) {
        // pack bf16 pairs (n-consecutive) into uint grid [fcol][n/2], stride 33
        unsigned int* SDH = (unsigned int*)smem;   // [64][33] = 8448 B
        #pragma unroll
        for (int c = 0; c < 4; ++c) {
            const int fl = c * 16 + lrow;
            const float bv = bsel[f0 + fl];
            #pragma unroll
            for (int p = 0; p < 2; ++p) {
                unsigned int pk = (unsigned int)f2bf(acc[c][2*p] + bv)
                                | ((unsigned int)f2bf(acc[c][2*p+1] + bv) << 16);
                SDH[fl * 33 + wid * 8 + quad * 2 + p] = pk;
            }
        }
        __syncthreads();
        const int f  = tid >> 2;
        const int ns = (tid & 3) * 16;
        unsigned int w[8];
        #pragma unroll
        for (int g = 0; g < 8; ++g) w[g] = SDH[f * 33 + ns / 2 + g];
        unsigned short* dst = H16T + (((size_t)b * NT + (ch - 1)) * FF + f0 + f) * NN + nb + ns;
        *reinterpret_cast<uint4*>(dst)     = (uint4){w[0], w[1], w[2], w[3]};
        *reinterpret_cast<uint4*>(dst + 8) = (uint4){w[4], w[5], w[6], w[7]};
    } else {
        // row-major f32 [n][fcol], stride 68 (2-way conflicts, free)
        float* SD = (float*)smem;                  // [64][68] = 17408 B
        #pragma unroll
        for (int c = 0; c < 4; ++c) {
            const int fl = c * 16 + lrow;
            float bv = bsel[f0 + fl];
            if (ch == 0) bv += bias_in[f0 + fl];
            #pragma unroll
            for (int r = 0; r < 4; ++r)
                SD[(wid * 16 + quad * 4 + r) * 68 + fl] = acc[c][r] + bv;
        }
        __syncthreads();
        if (ch == 0) {
            const int n  = tid >> 2;
            const int fs = (tid & 3) * 16;
            float* dst = out + (size_t)(m0 + n) * 128 + f0 + fs;
            #pragma unroll
            for (int g = 0; g < 4; ++g)
                reinterpret_cast<float4*>(dst)[g] =
                    *reinterpret_cast<const float4*>(&SD[n * 68 + fs + 4 * g]);
        } else {
            // ch 13: cols 2t -> el, 2t+1 -> er  (t = 0..11) + exp tables
            const int n  = tid >> 2;
            const int c3 = tid & 3;
            #pragma unroll
            for (int tt = 0; tt < 3; ++tt) {
                const int t = c3 * 3 + tt;
                const float ev = SD[n * 68 + 2 * t];
                const float rv = SD[n * 68 + 2 * t + 1];
                const size_t o = ((size_t)b * NT + t) * NN + nb + n;
                el[o] = ev;  xl[o] = __expf(ev);
                er[o] = rv;  xr[o] = __expf(rv);
            }
        }
    }
}

// ---------------------------------------------------------------------------
// K5-dense v5: branchless Q-build.
//  q = max( exp(el_i)*exp(er_j)*a , fma(a, 0.01*(el_i+er_j), 1) )
//  a in {0,1} exactly (binary adjacency; mode1 a = d_i*d_j). This selects:
//  a=0 -> 1; a=1,e>=0 -> exp(e); a=1,e<0 -> 1+0.01e ~= exp(0.01e) (err<8e-4
//  < bf16 ULP). No cmp/cndmask/transcendental in the j-loop. Cheap
//  round-half-up bf16 pair pack (pk2bf).
// ---------------------------------------------------------------------------
__global__ __launch_bounds__(256) void k5_dense(
    const float* __restrict__ adjs, const unsigned short* __restrict__ H16T,
    const float* __restrict__ el, const float* __restrict__ er,
    const float* __restrict__ xl, const float* __restrict__ xr,
    const float* __restrict__ dv, float* __restrict__ out)
{
    __shared__ __align__(16) unsigned short Hls[144][72];  // [f][j], rows 128+ = ones
    __shared__ float lls[128];

    const int tid  = threadIdx.x;
    const int lane = tid & 63;
    const int wv   = tid >> 6;
    const int bi   = blockIdx.x;
    const int b    = bi & 7;               // batch -> XCD
    const int q    = bi >> 3;              // 0..95
    const int tq   = q >> 3;               // 0..11 schedule slot
    // schedule {0..5,6,9,7,10,8,11}: fwd/bwd of same slab adjacent for L2 reuse
    const int t    = (tq < 6) ? tq : (6 + (tq - 6) / 2 + ((tq - 6) & 1) * 3);
    const int i0   = (q & 7) * 128;
    const int bt   = b * NT + t;

    const unsigned short* hb = H16T + (size_t)bt * FF * NN;
    const float* elp = el + (size_t)bt * NN;
    const float* erp = er + (size_t)bt * NN;
    const float* xrp = xr + (size_t)bt * NN;
    const float* dvp = dv + (size_t)(b * 3 + ((t - 3) % 3 + 3) % 3) * NN;

    int mode; const float* slab = nullptr;
    if (t < 3)       { mode = 0; slab = adjs + ((size_t)b * 9 + t) * (size_t)NN * NN; }
    else if (t < 6)  { mode = 1; }
    else if (t < 9)  { mode = 0; slab = adjs + ((size_t)b * 9 + t) * (size_t)NN * NN; }
    else             { mode = 2; slab = adjs + ((size_t)b * 9 + (t - 3)) * (size_t)NN * NN; }

    const int lrow = lane & 15;
    const int quad = lane >> 4;
    const int kq   = quad * 8;
    const int r0   = i0 + wv * 32 + lrow;
    const int r1   = r0 + 16;

    const float c0  = 0.01f * elp[r0];     // for the negative-branch linear term
    const float c1  = 0.01f * elp[r1];
    const float Ei0 = xl[(size_t)bt * NN + r0];
    const float Ei1 = xl[(size_t)bt * NN + r1];
    float gdv0 = 1.f, gdv1 = 1.f;
    if (mode == 1) { gdv0 = dvp[r0]; gdv1 = dvp[r1]; }   // exact 0/1

    // ones rows (128..143): row 128 = 1.0 for j<64, rest 0
    for (int idx = tid; idx < 16 * 72; idx += 256) {
        int r = idx / 72, k = idx % 72;
        Hls[128 + r][k] = (r == 0 && k < 64) ? (unsigned short)0x3F80u : (unsigned short)0u;
    }

    floatx4 acc[2][9];
    #pragma unroll
    for (int mt = 0; mt < 2; ++mt)
        #pragma unroll
        for (int nt = 0; nt < 9; ++nt) acc[mt][nt] = (floatx4){0.f, 0.f, 0.f, 0.f};

    union AFrag { unsigned int w[4]; bf16x8 v; };

    const int hf = tid >> 1;               // staging: thread -> H^T row
    const int jh = (tid & 1) * 32;

    for (int jt = 0; jt < 16; ++jt) {
        const int j0 = jt * 64;
        __syncthreads();                   // previous tile's Hls reads complete

        // issue H^T staging loads (land during frag build below)
        const unsigned short* hrow = hb + (size_t)hf * NN + j0 + jh;
        uint4 U0 = *reinterpret_cast<const uint4*>(hrow);
        uint4 U1 = *reinterpret_cast<const uint4*>(hrow + 8);
        uint4 U2 = *reinterpret_cast<const uint4*>(hrow + 16);
        uint4 U3 = *reinterpret_cast<const uint4*>(hrow + 24);

        // build A-fragments in registers (branchless)
        AFrag af[2][2];                    // [mt][kh]
        #pragma unroll
        for (int kh = 0; kh < 2; ++kh) {
            const int jb = j0 + kh * 32 + kq;
            float4 eA = *reinterpret_cast<const float4*>(erp + jb);
            float4 eB = *reinterpret_cast<const float4*>(erp + jb + 4);
            float ee[8] = {eA.x, eA.y, eA.z, eA.w, eB.x, eB.y, eB.z, eB.w};
            float4 xA = *reinterpret_cast<const float4*>(xrp + jb);
            float4 xB = *reinterpret_cast<const float4*>(xrp + jb + 4);
            float xx[8] = {xA.x, xA.y, xA.z, xA.w, xB.x, xB.y, xB.z, xB.w};
            float a0[8], a1[8];
            if (mode == 0) {
                float4 A0 = *reinterpret_cast<const float4*>(slab + (size_t)r0 * NN + jb);
                float4 A1 = *reinterpret_cast<const float4*>(slab + (size_t)r0 * NN + jb + 4);
                float4 B0 = *reinterpret_cast<const float4*>(slab + (size_t)r1 * NN + jb);
                float4 B1 = *reinterpret_cast<const float4*>(slab + (size_t)r1 * NN + jb + 4);
                a0[0]=A0.x;a0[1]=A0.y;a0[2]=A0.z;a0[3]=A0.w;a0[4]=A1.x;a0[5]=A1.y;a0[6]=A1.z;a0[7]=A1.w;
                a1[0]=B0.x;a1[1]=B0.y;a1[2]=B0.z;a1[3]=B0.w;a1[4]=B1.x;a1[5]=B1.y;a1[6]=B1.z;a1[7]=B1.w;
            } else if (mode == 1) {
                float4 D0 = *reinterpret_cast<const float4*>(dvp + jb);
                float4 D1 = *reinterpret_cast<const float4*>(dvp + jb + 4);
                float d8[8] = {D0.x,D0.y,D0.z,D0.w,D1.x,D1.y,D1.z,D1.w};
                #pragma unroll
                for (int g = 0; g < 8; ++g) { a0[g] = d8[g] * gdv0; a1[g] = d8[g] * gdv1; }
            } else {
                #pragma unroll
                for (int g = 0; g < 8; ++g) {
                    const float* col = slab + (size_t)(jb + g) * NN;
                    a0[g] = col[r0];       // lanes of a quad read 16 consecutive i
                    a1[g] = col[r1];
                }
            }
            #pragma unroll
            for (int gp = 0; gp < 4; ++gp) {
                float q0[2], q1[2];
                #pragma unroll
                for (int h = 0; h < 2; ++h) {
                    const int g = 2 * gp + h;
                    const float ez = 0.01f * ee[g];
                    q0[h] = fmaxf(Ei0 * xx[g] * a0[g], fmaf(a0[g], c0 + ez, 1.0f));
                    q1[h] = fmaxf(Ei1 * xx[g] * a1[g], fmaf(a1[g], c1 + ez, 1.0f));
                }
                af[0][kh].w[gp] = pk2bf(q0[0], q0[1]);
                af[1][kh].w[gp] = pk2bf(q1[0], q1[1]);
            }
        }

        // commit H^T tile to LDS (loads have landed by now)
        *reinterpret_cast<uint4*>(&Hls[hf][jh])      = U0;
        *reinterpret_cast<uint4*>(&Hls[hf][jh + 8])  = U1;
        *reinterpret_cast<uint4*>(&Hls[hf][jh + 16]) = U2;
        *reinterpret_cast<uint4*>(&Hls[hf][jh + 24]) = U3;
        __syncthreads();

        // MFMA: 2 kh x 9 nt x 2 mt
        #pragma unroll
        for (int kh = 0; kh < 2; ++kh) {
            const int k0 = kh * 32 + kq;
            #pragma unroll
            for (int nt = 0; nt < 9; ++nt) {
                bf16x8 bfr = *reinterpret_cast<const bf16x8*>(&Hls[nt * 16 + lrow][k0]);
                acc[0][nt] = __builtin_amdgcn_mfma_f32_16x16x32_bf16(af[0][kh].v, bfr, acc[0][nt], 0, 0, 0);
                acc[1][nt] = __builtin_amdgcn_mfma_f32_16x16x32_bf16(af[1][kh].v, bfr, acc[1][nt], 0, 0, 0);
            }
        }
    }

    // ---- epilogue: l from n-tile 8 (col 0), scale, atomic add ----
    if (lrow == 0) {
        #pragma unroll
        for (int mt = 0; mt < 2; ++mt)
            #pragma unroll
            for (int r = 0; r < 4; ++r)
                lls[wv * 32 + mt * 16 + quad * 4 + r] = acc[mt][8][r];
    }
    __syncthreads();

    const float scale = (t >= 6) ? 0.5f : 1.0f;
    float* ob = out + ((size_t)b * NN + i0) * FF;
    #pragma unroll
    for (int mt = 0; mt < 2; ++mt) {
        #pragma unroll
        for (int r = 0; r < 4; ++r) {
            const int m = wv * 32 + mt * 16 + quad * 4 + r;
            const float inv = scale / lls[m];
            #pragma unroll
            for (int nt = 0; nt < 8; ++nt)
                atomicAdd(&ob[(size_t)m * FF + nt * 16 + lrow], acc[mt][nt][r] * inv);
        }
    }
}

// ---------------------------------------------------------------------------
// K6: relu in place
// ---------------------------------------------------------------------------
__global__ __launch_bounds__(256) void k6_relu(float* __restrict__ out)
{
    const int gid = blockIdx.x * 256 + threadIdx.x;
    out[gid] = fmaxf(out[gid], 0.f);
}

extern "C" void kernel_launch(void* const* d_in, const int* in_sizes, int n_in,
                              void* d_out, int out_size, void* d_ws, size_t ws_size,
                              hipStream_t stream)
{
    const float* x         = (const float*)d_in[0];
    const float* adjs      = (const float*)d_in[1];
    const float* fc_w      = (const float*)d_in[2];
    const float* fc_b      = (const float*)d_in[3];
    const float* att_w     = (const float*)d_in[4];
    const float* att_b     = (const float*)d_in[5];
    const float* fwd_fc_w  = (const float*)d_in[6];
    const float* fwd_fc_b  = (const float*)d_in[7];
    const float* fwd_att_w = (const float*)d_in[8];
    const float* fwd_att_b = (const float*)d_in[9];
    const float* bwd_fc_w  = (const float*)d_in[10];
    const float* bwd_fc_b  = (const float*)d_in[11];
    const float* bwd_att_w = (const float*)d_in[12];
    const float* bwd_att_b = (const float*)d_in[13];
    const float* self_w    = (const float*)d_in[14];
    const float* self_b    = (const float*)d_in[15];
    const float* bias_in   = (const float*)d_in[16];
    float* out = (float*)d_out;

    char* ws = (char*)d_ws;
    unsigned short* H16T = (unsigned short*)(ws + H_OFF);
    float* el = (float*)(ws + EL_OFF);
    float* er = (float*)(ws + ER_OFF);
    float* dv = (float*)(ws + DV_OFF);
    float* FV = (float*)(ws + FV_OFF);
    float* FB = (float*)(ws + FB_OFF);
    float* xl = (float*)(ws + XL_OFF);
    float* xr = (float*)(ws + XR_OFF);

    // K0: folded attention vectors + biases + diagonals
    k0_setup<<<160, 256, 0, stream>>>(adjs, fc_w, fc_b, att_w, att_b,
                                      fwd_att_w, fwd_att_b, bwd_att_w, bwd_att_b,
                                      FV, FB, dv);

    // K1: 14-channel projection GEMM (ch0 -> out, 1..12 -> H^T, 13 -> el/er/exp)
    k1_gemm<<<dim3(27, 128), 256, 0, stream>>>(
        x, fc_w, fc_b, fwd_fc_w, fwd_fc_b, bwd_fc_w, bwd_fc_b,
        self_w, self_b, bias_in, FV, FB, out, H16T, el, er, xl, xr);

    // K5: dense MFMA attention-apply, branchless Q-build
    k5_dense<<<BB * NT * 8, 256, 0, stream>>>(adjs, H16T, el, er, xl, xr, dv, out);

    // K6: relu
    k6_relu<<<out_size / 256, 256, 0, stream>>>(out);
}